// Round 6
// baseline (263.564 us; speedup 1.0000x reference)
//
#include <hip/hip_runtime.h>
#include <hip/hip_bf16.h>
#include <math.h>

#define T_DIM 1024
#define B_DIM 32
#define DIMF 512
#define DIMH 512
#define DIMS 1024
#define DIMW 512

typedef __attribute__((ext_vector_type(8))) short short8;
typedef __attribute__((ext_vector_type(4))) float f32x4;

__device__ __forceinline__ unsigned f2bf1(float x) {
    unsigned a = __float_as_uint(x);
    return (a + 0x7FFFu + ((a >> 16) & 1u)) >> 16;
}
__device__ __forceinline__ unsigned f2bf2(float lo, float hi) {
    return f2bf1(lo) | (f2bf1(hi) << 16);
}
__device__ __forceinline__ float fast_tanh(float x) {
    return 1.f - __fdividef(2.f, 1.f + __expf(x + x));
}
__device__ __forceinline__ unsigned short bf1(float x) {
    __hip_bfloat16 b = __float2bfloat16(x);
    return *reinterpret_cast<unsigned short*>(&b);
}
// load 8 f32 -> bf16 short8 fragment (compiler packs casts to v_cvt_pk_bf16_f32)
__device__ __forceinline__ short8 cvt_frag(const float* p) {
    const float4 a = *(const float4*)p;
    const float4 c = *(const float4*)(p + 4);
    union { unsigned short us[8]; short8 s; } u;
    u.us[0] = bf1(a.x); u.us[1] = bf1(a.y); u.us[2] = bf1(a.z); u.us[3] = bf1(a.w);
    u.us[4] = bf1(c.x); u.us[5] = bf1(c.y); u.us[6] = bf1(c.z); u.us[7] = bf1(c.w);
    return u.s;
}

// ---- GT[w][k] = bf16((F@Uw)^T), plain row-major [DIMW][T_DIM-k... K=1024? no: K rows of G are T rows]
// G is [T=1024][W=512]; GT is [W=512][1024]
__global__ void k_G_gt(const float* __restrict__ F, const float* __restrict__ Uw,
                       unsigned short* __restrict__ GT) {
    __shared__ float Fs[16][DIMF];
    const int r0 = blockIdx.x * 16;
    const int c  = blockIdx.y * 256 + threadIdx.x;
    const float4* Fv  = (const float4*)(F + (size_t)r0 * DIMF);
    float4* Fsv = (float4*)&Fs[0][0];
    for (int i = threadIdx.x; i < 16 * DIMF / 4; i += 256) Fsv[i] = Fv[i];
    __syncthreads();
    float acc[16];
#pragma unroll
    for (int r = 0; r < 16; ++r) acc[r] = 0.f;
    for (int k = 0; k < DIMF; ++k) {
        const float bv = Uw[(size_t)k * DIMW + c];
#pragma unroll
        for (int r = 0; r < 16; ++r) acc[r] = fmaf(Fs[r][k], bv, acc[r]);
    }
    uint4 o0, o1;
    o0.x = f2bf2(acc[0], acc[1]);   o0.y = f2bf2(acc[2], acc[3]);
    o0.z = f2bf2(acc[4], acc[5]);   o0.w = f2bf2(acc[6], acc[7]);
    o1.x = f2bf2(acc[8], acc[9]);   o1.y = f2bf2(acc[10], acc[11]);
    o1.z = f2bf2(acc[12], acc[13]); o1.w = f2bf2(acc[14], acc[15]);
    *(uint4*)(GT + (size_t)c * T_DIM + r0)     = o0;
    *(uint4*)(GT + (size_t)c * T_DIM + r0 + 8) = o1;
}

// ---- SWp[q][b][c] partial of s_prev@Ww (+Vb at q==0), grid (32,4) ----
__global__ void k_SW(const float* __restrict__ s_prev, const float* __restrict__ Ww,
                     const float* __restrict__ Vb, float* __restrict__ SWp) {
    __shared__ float ss[256];
    const int b = blockIdx.x, q = blockIdx.y;
    if (threadIdx.x < 64)
        ((float4*)ss)[threadIdx.x] =
            ((const float4*)(s_prev + (size_t)b * DIMS + q * 256))[threadIdx.x];
    __syncthreads();
    const int c0 = threadIdx.x, c1 = threadIdx.x + 256;
    float a0 = (q == 0) ? Vb[c0] : 0.f;
    float a1 = (q == 0) ? Vb[c1] : 0.f;
    const float* W = Ww + (size_t)q * 256 * DIMW;
    for (int k = 0; k < 256; ++k) {
        const float sv = ss[k];
        a0 = fmaf(sv, W[(size_t)k * DIMW + c0], a0);
        a1 = fmaf(sv, W[(size_t)k * DIMW + c1], a1);
    }
    SWp[((size_t)q * B_DIM + b) * DIMW + c0] = a0;
    SWp[((size_t)q * B_DIM + b) * DIMW + c1] = a1;
}

// ---- VwT[n][k] = bf16(Vw[k][n]) plain ----
__global__ void k_pack_vwT(const float* __restrict__ Vw, unsigned short* __restrict__ VwT) {
    __shared__ float t[32][33];
    const int k0 = blockIdx.x * 32, n0 = blockIdx.y * 32;
    const int x = threadIdx.x & 31, y = threadIdx.x >> 5;
#pragma unroll
    for (int i = 0; i < 4; ++i)
        t[y + 8 * i][x] = Vw[(size_t)(k0 + y + 8 * i) * DIMW + n0 + x];
    __syncthreads();
#pragma unroll
    for (int i = 0; i < 4; ++i) {
        const int n = n0 + y + 8 * i;
        VwT[(size_t)n * DIMH + k0 + x] = (unsigned short)f2bf1(t[x][y + 8 * i]);
    }
}

// ---- P[b][s][i] = bf16(a_logical[b][i+s]), 8 staggered copies ----
__global__ void k_pack_a(const float* __restrict__ a_prev, unsigned short* __restrict__ P) {
    const int bs = blockIdx.x;
    const int b = bs >> 3, s = bs & 7;
    for (int i = threadIdx.x; i < 2048; i += 256) {
        const int j = i + s;
        float v = 0.f;
        if (j >= 512 && j < 1536) v = a_prev[(size_t)b * T_DIM + j - 512];
        P[(size_t)bs * 2048 + i] = (unsigned short)f2bf1(v);
    }
}

// ---------------- main MFMA kernel: register-direct, barrier-free ----------------
// grid 1024 (XCD-swizzled), 256 threads (4 waves 2x2), tile 128x128
__global__ void __launch_bounds__(256, 2) k_main(
    const float* __restrict__ hF, const unsigned short* __restrict__ VwT,
    const unsigned short* __restrict__ GT, const unsigned short* __restrict__ P,
    const float* __restrict__ SWp, const float* __restrict__ ww,
    float* __restrict__ ep) {

    const int bid = blockIdx.x;
    const int wg  = (bid & 7) * 128 + (bid >> 3);   // bijective: 1024 % 8 == 0
    const int x = wg & 3, y = wg >> 2;
    const int w0 = x * 128;
    const int b  = y >> 3;
    const int t0 = (y & 7) * 128;

    const int tid  = threadIdx.x;
    const int lane = tid & 63;
    const int wv   = tid >> 6;
    const int wm = wv >> 1, wn = wv & 1;
    const int g = lane >> 4, r16 = lane & 15;
    const int g8 = g * 8;

    f32x4 acc[4][4];
#pragma unroll
    for (int m = 0; m < 4; ++m)
#pragma unroll
        for (int n = 0; n < 4; ++n) acc[m][n] = (f32x4)0.f;

    // per-lane source pointers
    const int trow0 = t0 + wm * 64 + r16;           // + m*16
    const int colB0 = w0 + wn * 64 + r16;           // + n*16
    const float* hA[4];
    const unsigned short* vB[4];
#pragma unroll
    for (int m = 0; m < 4; ++m)
        hA[m] = hF + ((size_t)(trow0 + m * 16) * B_DIM + b) * DIMH + g8;
#pragma unroll
    for (int n = 0; n < 4; ++n)
        vB[n] = VwT + (size_t)(colB0 + n * 16) * DIMH + g8;

    const int kstart = max(0, t0 - 512);
    const int kend   = min(T_DIM - 1, t0 + 639);
    const int NS2    = (kend - kstart + 1) >> 5;    // even, >= 20
    const unsigned short* Pb = P + (size_t)b * 8 * 2048;
    const unsigned short* pA[4];
    const unsigned short* gB[4];
#pragma unroll
    for (int m = 0; m < 4; ++m) {
        const int trow = trow0 + m * 16;
        const int j0 = kstart + g8 + 1024 - trow;   // in [1, 2040]
        const int sj = j0 & 7;
        pA[m] = Pb + sj * 2048 + (j0 - sj);
    }
#pragma unroll
    for (int n = 0; n < 4; ++n)
        gB[n] = GT + (size_t)(colB0 + n * 16) * T_DIM + kstart + g8;

    const bool zrow = (trow0 == 0);                 // only m==0 can be row 0

    short8 afP[4], bfP[4], afQ[4], bfQ[4];

#define LOAD1(AF, BF, S)                                               \
    {                                                                  \
        const int _o = (S) * 32;                                       \
        _Pragma("unroll")                                              \
        for (int m = 0; m < 4; ++m) AF[m] = cvt_frag(hA[m] + _o);      \
        _Pragma("unroll")                                              \
        for (int n = 0; n < 4; ++n) BF[n] = *(const short8*)(vB[n] + _o); \
    }
#define LOAD2(AF, BF, S)                                               \
    {                                                                  \
        const int _o = (S) * 32;                                       \
        _Pragma("unroll")                                              \
        for (int m = 0; m < 4; ++m) AF[m] = *(const short8*)(pA[m] + _o); \
        if (zrow) AF[0] = (short8)(short)0;                            \
        _Pragma("unroll")                                              \
        for (int n = 0; n < 4; ++n) BF[n] = *(const short8*)(gB[n] + _o); \
    }
#define MFMA16(AF, BF)                                                 \
    {                                                                  \
        _Pragma("unroll")                                              \
        for (int m = 0; m < 4; ++m)                                    \
            _Pragma("unroll")                                          \
            for (int n = 0; n < 4; ++n)                                \
                acc[m][n] = __builtin_amdgcn_mfma_f32_16x16x32_bf16(   \
                    AF[m], BF[n], acc[m][n], 0, 0, 0);                 \
    }

    // ---- part 1: h^T @ Vw, 16 K-steps, 2-deep prefetch ----
    LOAD1(afP, bfP, 0);
    for (int s = 0; s < 14; s += 2) {
        LOAD1(afQ, bfQ, s + 1);
        MFMA16(afP, bfP);
        LOAD1(afP, bfP, s + 2);
        MFMA16(afQ, bfQ);
    }
    LOAD1(afQ, bfQ, 15);
    MFMA16(afP, bfP);
    LOAD2(afP, bfP, 0);          // chain: prefetch part2 step 0
    MFMA16(afQ, bfQ);

    // ---- part 2: Toeplitz(a) @ G, NS2 K-steps ----
    for (int s = 0; s < NS2 - 2; s += 2) {
        LOAD2(afQ, bfQ, s + 1);
        MFMA16(afP, bfP);
        LOAD2(afP, bfP, s + 2);
        MFMA16(afQ, bfQ);
    }
    LOAD2(afQ, bfQ, NS2 - 1);
    MFMA16(afP, bfP);
    MFMA16(afQ, bfQ);

#undef LOAD1
#undef LOAD2
#undef MFMA16

    // ---- epilogue: tanh, dot ww, 16-lane reduce, per-(x,wn) partial store ----
    float swv[4], wwv[4];
#pragma unroll
    for (int n = 0; n < 4; ++n) {
        const int w = w0 + wn * 64 + n * 16 + r16;
        float sv = 0.f;
#pragma unroll
        for (int q = 0; q < 4; ++q)
            sv += SWp[((size_t)q * B_DIM + b) * DIMW + w];
        swv[n] = sv;
        wwv[n] = ww[w];
    }
#pragma unroll
    for (int m = 0; m < 4; ++m) {
#pragma unroll
        for (int reg = 0; reg < 4; ++reg) {
            float s = 0.f;
#pragma unroll
            for (int n = 0; n < 4; ++n)
                s = fmaf(fast_tanh(acc[m][n][reg] + swv[n]), wwv[n], s);
            s += __shfl_xor(s, 1, 64);
            s += __shfl_xor(s, 2, 64);
            s += __shfl_xor(s, 4, 64);
            s += __shfl_xor(s, 8, 64);
            if (r16 == 0) {
                const int trow = t0 + wm * 64 + m * 16 + g * 4 + reg;
                ep[((size_t)(x * 2 + wn) * B_DIM + b) * T_DIM + trow] = s;
            }
        }
    }
}

// ---------------- softmax over t per batch (sums 8 e-partials) ----------------
__device__ __forceinline__ float decode_beta(const void* p) {
    const int iv = *(const int*)p;
    const float fv = __int_as_float(iv);
    const float afv = fabsf(fv);
    if (afv >= 1e-6f && afv <= 1e6f) return fv;
    return (float)iv;
}

__global__ void k_softmax(const float* __restrict__ ep, const void* __restrict__ beta_p,
                          float* __restrict__ out) {
    const int b = blockIdx.x;
    const float beta = decode_beta(beta_p);
    __shared__ float redm[4];
    __shared__ float reds[4];
    float v[4];
    float m = -INFINITY;
#pragma unroll
    for (int i = 0; i < 4; ++i) {
        const int t = threadIdx.x * 4 + i;
        float ev = 0.f;
#pragma unroll
        for (int xq = 0; xq < 8; ++xq)
            ev += ep[((size_t)xq * B_DIM + b) * T_DIM + t];
        v[i] = beta * ev;
        m = fmaxf(m, v[i]);
    }
    for (int off = 1; off < 64; off <<= 1) m = fmaxf(m, __shfl_xor(m, off, 64));
    const int wid = threadIdx.x >> 6, lane = threadIdx.x & 63;
    if (lane == 0) redm[wid] = m;
    __syncthreads();
    m = fmaxf(fmaxf(redm[0], redm[1]), fmaxf(redm[2], redm[3]));
    float s = 0.f;
    float ex[4];
#pragma unroll
    for (int i = 0; i < 4; ++i) { ex[i] = expf(v[i] - m); s += ex[i]; }
    for (int off = 1; off < 64; off <<= 1) s += __shfl_xor(s, off, 64);
    if (lane == 0) reds[wid] = s;
    __syncthreads();
    s = reds[0] + reds[1] + reds[2] + reds[3];
    const float inv = 1.f / s;
#pragma unroll
    for (int i = 0; i < 4; ++i)
        out[(size_t)b * T_DIM + threadIdx.x * 4 + i] = ex[i] * inv;
}

extern "C" void kernel_launch(void* const* d_in, const int* in_sizes, int n_in,
                              void* d_out, int out_size, void* d_ws, size_t ws_size,
                              hipStream_t stream) {
    const float* F      = (const float*)d_in[0];
    const float* a_prev = (const float*)d_in[1];
    const float* s_prev = (const float*)d_in[2];
    const float* h      = (const float*)d_in[3];
    const float* Ww     = (const float*)d_in[4];
    const float* Vw     = (const float*)d_in[5];
    const float* Vb     = (const float*)d_in[6];
    const float* Uw     = (const float*)d_in[7];
    const float* ww     = (const float*)d_in[8];
    const void*  beta_p = d_in[9];
    float* out = (float*)d_out;

    char* ws = (char*)d_ws;
    unsigned short* GT  = (unsigned short*)(ws);                        // 1 MB
    unsigned short* VwT = (unsigned short*)(ws + (1u << 20));           // 512 KB
    unsigned short* P   = (unsigned short*)(ws + (1u << 20) + (512u << 10));  // 1 MB
    float* SWp = (float*)(ws + (2u << 20) + (512u << 10));              // 256 KB
    float* ep  = (float*)(ws + (2u << 20) + (768u << 10));              // 1 MB (8 partials)

    k_G_gt    <<<dim3(64, 2),  256, 0, stream>>>(F, Uw, GT);
    k_pack_vwT<<<dim3(16, 16), 256, 0, stream>>>(Vw, VwT);
    k_pack_a  <<<dim3(256),    256, 0, stream>>>(a_prev, P);
    k_SW      <<<dim3(32, 4),  256, 0, stream>>>(s_prev, Ww, Vb, SWp);
    k_main    <<<dim3(1024),   256, 0, stream>>>(h, VwT, GT, P, SWp, ww, ep);
    k_softmax <<<dim3(32),     256, 0, stream>>>(ep, beta_p, out);
}

// Round 7
// 194.253 us; speedup vs baseline: 1.3568x; 1.3568x over previous
//
#include <hip/hip_runtime.h>
#include <hip/hip_bf16.h>
#include <math.h>

#define T_DIM 1024
#define B_DIM 32
#define DIMF 512
#define DIMH 512
#define DIMS 1024
#define DIMW 512

typedef __attribute__((ext_vector_type(8))) short short8;
typedef __attribute__((ext_vector_type(4))) float f32x4;

__device__ __forceinline__ unsigned f2bf1(float x) {
    unsigned a = __float_as_uint(x);
    return (a + 0x7FFFu + ((a >> 16) & 1u)) >> 16;
}
__device__ __forceinline__ unsigned f2bf2(float lo, float hi) {
    return f2bf1(lo) | (f2bf1(hi) << 16);
}
__device__ __forceinline__ float fast_tanh(float x) {
    return 1.f - __fdividef(2.f, 1.f + __expf(x + x));
}
__device__ __forceinline__ unsigned short bf1(float x) {
    __hip_bfloat16 b = __float2bfloat16(x);
    return *reinterpret_cast<unsigned short*>(&b);
}
__device__ __forceinline__ short8 cvt_frag(const float* p) {
    const float4 a = *(const float4*)p;
    const float4 c = *(const float4*)(p + 4);
    union { unsigned short us[8]; short8 s; } u;
    u.us[0] = bf1(a.x); u.us[1] = bf1(a.y); u.us[2] = bf1(a.z); u.us[3] = bf1(a.w);
    u.us[4] = bf1(c.x); u.us[5] = bf1(c.y); u.us[6] = bf1(c.z); u.us[7] = bf1(c.w);
    return u.s;
}

// async global->LDS, 16B per lane; LDS dest wave-uniform (lane*16B implicit), global src per-lane
__device__ __forceinline__ void gl16(const unsigned short* g, unsigned short* l) {
    __builtin_amdgcn_global_load_lds(
        (const __attribute__((address_space(1))) unsigned int*)g,
        (__attribute__((address_space(3))) unsigned int*)l, 16, 0, 0);
}

// ---- GT[w][k ^ ((w&3)<<3)] = bf16((F@Uw)^T), chunk-swizzled (r5-verified) ----
__global__ void k_G_gt(const float* __restrict__ F, const float* __restrict__ Uw,
                       unsigned short* __restrict__ GT) {
    __shared__ float Fs[16][DIMF];
    const int r0 = blockIdx.x * 16;
    const int c  = blockIdx.y * 256 + threadIdx.x;
    const float4* Fv  = (const float4*)(F + (size_t)r0 * DIMF);
    float4* Fsv = (float4*)&Fs[0][0];
    for (int i = threadIdx.x; i < 16 * DIMF / 4; i += 256) Fsv[i] = Fv[i];
    __syncthreads();
    float acc[16];
#pragma unroll
    for (int r = 0; r < 16; ++r) acc[r] = 0.f;
    for (int k = 0; k < DIMF; ++k) {
        const float bv = Uw[(size_t)k * DIMW + c];
#pragma unroll
        for (int r = 0; r < 16; ++r) acc[r] = fmaf(Fs[r][k], bv, acc[r]);
    }
    uint4 o0, o1;
    o0.x = f2bf2(acc[0], acc[1]);   o0.y = f2bf2(acc[2], acc[3]);
    o0.z = f2bf2(acc[4], acc[5]);   o0.w = f2bf2(acc[6], acc[7]);
    o1.x = f2bf2(acc[8], acc[9]);   o1.y = f2bf2(acc[10], acc[11]);
    o1.z = f2bf2(acc[12], acc[13]); o1.w = f2bf2(acc[14], acc[15]);
    const int s3 = (c & 3) << 3;
    unsigned short* gout = GT + (size_t)c * T_DIM + (r0 & ~31);
    const int off0 = (r0 & 31) ^ s3;
    *(uint4*)(gout + off0)       = o0;
    *(uint4*)(gout + (off0 ^ 8)) = o1;
}

// ---- SWp[q][b][c] partial of s_prev@Ww (+Vb at q==0), grid (32,4) ----
__global__ void k_SW(const float* __restrict__ s_prev, const float* __restrict__ Ww,
                     const float* __restrict__ Vb, float* __restrict__ SWp) {
    __shared__ float ss[256];
    const int b = blockIdx.x, q = blockIdx.y;
    if (threadIdx.x < 64)
        ((float4*)ss)[threadIdx.x] =
            ((const float4*)(s_prev + (size_t)b * DIMS + q * 256))[threadIdx.x];
    __syncthreads();
    const int c0 = threadIdx.x, c1 = threadIdx.x + 256;
    float a0 = (q == 0) ? Vb[c0] : 0.f;
    float a1 = (q == 0) ? Vb[c1] : 0.f;
    const float* W = Ww + (size_t)q * 256 * DIMW;
    for (int k = 0; k < 256; ++k) {
        const float sv = ss[k];
        a0 = fmaf(sv, W[(size_t)k * DIMW + c0], a0);
        a1 = fmaf(sv, W[(size_t)k * DIMW + c1], a1);
    }
    SWp[((size_t)q * B_DIM + b) * DIMW + c0] = a0;
    SWp[((size_t)q * B_DIM + b) * DIMW + c1] = a1;
}

// ---- VwT[n][k ^ ((n&3)<<3)] = bf16(Vw[k][n]) chunk-swizzled (r5-verified) ----
__global__ void k_pack_vwT(const float* __restrict__ Vw, unsigned short* __restrict__ VwT) {
    __shared__ float t[32][33];
    const int k0 = blockIdx.x * 32, n0 = blockIdx.y * 32;
    const int x = threadIdx.x & 31, y = threadIdx.x >> 5;
#pragma unroll
    for (int i = 0; i < 4; ++i)
        t[y + 8 * i][x] = Vw[(size_t)(k0 + y + 8 * i) * DIMW + n0 + x];
    __syncthreads();
#pragma unroll
    for (int i = 0; i < 4; ++i) {
        const int n = n0 + y + 8 * i;
        const int kk = (k0 + x) ^ ((n & 3) << 3);
        VwT[(size_t)n * DIMH + kk] = (unsigned short)f2bf1(t[x][y + 8 * i]);
    }
}

// ---- P[b][s][i] = bf16(a_logical[b][i+s]), 8 staggered copies ----
__global__ void k_pack_a(const float* __restrict__ a_prev, unsigned short* __restrict__ P) {
    const int bs = blockIdx.x;
    const int b = bs >> 3, s = bs & 7;
    for (int i = threadIdx.x; i < 2048; i += 256) {
        const int j = i + s;
        float v = 0.f;
        if (j >= 512 && j < 1536) v = a_prev[(size_t)b * T_DIM + j - 512];
        P[(size_t)bs * 2048 + i] = (unsigned short)f2bf1(v);
    }
}

// ---- hB[(b,t)][k] = bf16(h[t][b][k]), 16B stores ----
__global__ void k_pack_h(const float* __restrict__ h, unsigned short* __restrict__ hB) {
    for (unsigned i = blockIdx.x * 256 + threadIdx.x; i < 32768u * 64; i += gridDim.x * 256) {
        const int r = i >> 6, c8 = (i & 63) * 8;
        const int bb = r >> 10, t = r & 1023;
        const float* src = h + ((size_t)(t * 32 + bb)) * 512 + c8;
        const float4 v0 = *(const float4*)(src);
        const float4 v1 = *(const float4*)(src + 4);
        union { unsigned short us[8]; uint4 u4; } o;
        o.us[0] = (unsigned short)f2bf1(v0.x); o.us[1] = (unsigned short)f2bf1(v0.y);
        o.us[2] = (unsigned short)f2bf1(v0.z); o.us[3] = (unsigned short)f2bf1(v0.w);
        o.us[4] = (unsigned short)f2bf1(v1.x); o.us[5] = (unsigned short)f2bf1(v1.y);
        o.us[6] = (unsigned short)f2bf1(v1.z); o.us[7] = (unsigned short)f2bf1(v1.w);
        *(uint4*)(hB + (size_t)r * 512 + c8) = o.u4;
    }
}

// ---------------- main MFMA kernel: A in regs, B via gl16 3-ring, counted vmcnt ----------------
// grid 1024 (XCD-swizzled), 256 threads (4 waves 2x2), tile 128x128
template <bool PACKED>
__global__ void __launch_bounds__(256) k_main(
    const float* __restrict__ hF, const unsigned short* __restrict__ hB,
    const unsigned short* __restrict__ VwT, const unsigned short* __restrict__ GT,
    const unsigned short* __restrict__ P, const float* __restrict__ SWp,
    const float* __restrict__ ww, float* __restrict__ ep) {
    __shared__ unsigned short Bs[3][128 * 32];   // 24 KB ring

    const int bid = blockIdx.x;
    const int wg  = (bid & 7) * 128 + (bid >> 3);   // bijective: 1024 % 8 == 0
    const int x = wg & 3, yy = wg >> 2;
    const int w0 = x * 128;
    const int b  = yy >> 3;
    const int t0 = (yy & 7) * 128;

    const int tid  = threadIdx.x;
    const int lane = tid & 63;
    const int wv   = tid >> 6;
    const int wm = wv >> 1, wn = wv & 1;
    const int g = lane >> 4, r16 = lane & 15, g8 = g * 8;
    const int rowc = lane >> 2, kq = lane & 3;
    const int gx = g8 ^ ((r16 & 3) << 3);           // swizzled frag-read chunk

    f32x4 acc[4][4];
#pragma unroll
    for (int m = 0; m < 4; ++m)
#pragma unroll
        for (int n = 0; n < 4; ++n) acc[m][n] = (f32x4)0.f;

    // ---- A sources (per-lane, register path) ----
    const int trow0 = t0 + wm * 64 + r16;
    const unsigned short* hA[4];
    const float* hAf[4];
#pragma unroll
    for (int m = 0; m < 4; ++m) {
        hA[m]  = hB + ((size_t)(b * 1024 + trow0 + m * 16)) * 512 + g8;
        hAf[m] = hF + ((size_t)(trow0 + m * 16) * B_DIM + b) * DIMH + g8;
    }
    const int kstart = max(0, t0 - 512);
    const int kend   = min(T_DIM - 1, t0 + 639);
    const int NS2    = (kend - kstart + 1) >> 5;    // even
    const int NT     = 16 + NS2;                    // even, 36..48
    const unsigned short* Pb = P + (size_t)b * 8 * 2048;
    const unsigned short* pA[4];
#pragma unroll
    for (int m = 0; m < 4; ++m) {
        const int trow = trow0 + m * 16;
        const int j0 = kstart + g8 + 1024 - trow;   // in [1, 2040]
        const int sj = j0 & 7;
        pA[m] = Pb + sj * 2048 + (j0 - sj);
    }
    const bool zrow = (trow0 == 0);

    // ---- B staging sources ----
    const int rB = wv * 32 + rowc;
    const unsigned short* vsrc = VwT + (size_t)(w0 + rB) * DIMH + kq * 8;
    const unsigned short* gsrc = GT  + (size_t)(w0 + rB) * T_DIM + kstart + kq * 8;

#define STAGEB(u2, j)                                                     \
    {                                                                     \
        if ((u2) < 16) {                                                  \
            const unsigned short* s_ = vsrc + (u2) * 32;                  \
            gl16(s_, &Bs[j][wv * 1024]);                                  \
            gl16(s_ + 16 * DIMH, &Bs[j][wv * 1024 + 512]);                \
        } else {                                                          \
            const unsigned short* s_ = gsrc + ((u2) - 16) * 32;           \
            gl16(s_, &Bs[j][wv * 1024]);                                  \
            gl16(s_ + 16 * T_DIM, &Bs[j][wv * 1024 + 512]);               \
        }                                                                 \
    }
#define LOADA(AF, u1)                                                     \
    {                                                                     \
        if ((u1) < 16) {                                                  \
            if (PACKED) {                                                 \
                _Pragma("unroll")                                         \
                for (int m = 0; m < 4; ++m)                               \
                    AF[m] = *(const short8*)(hA[m] + (u1) * 32);          \
            } else {                                                      \
                _Pragma("unroll")                                         \
                for (int m = 0; m < 4; ++m)                               \
                    AF[m] = cvt_frag(hAf[m] + (u1) * 32);                 \
            }                                                             \
        } else {                                                          \
            _Pragma("unroll")                                             \
            for (int m = 0; m < 4; ++m)                                   \
                AF[m] = *(const short8*)(pA[m] + ((u1) - 16) * 32);       \
            if (zrow) AF[0] = (short8)(short)0;                           \
        }                                                                 \
    }
#define MFMA16(AF, BF)                                                    \
    {                                                                     \
        _Pragma("unroll")                                                 \
        for (int m = 0; m < 4; ++m)                                       \
            _Pragma("unroll")                                             \
            for (int n = 0; n < 4; ++n)                                   \
                acc[m][n] = __builtin_amdgcn_mfma_f32_16x16x32_bf16(      \
                    AF[m], BF[n], acc[m][n], 0, 0, 0);                    \
    }
// steady-state future in-flight: 2 gl16(u+2) + A(u+1) loads (4 packed / 8 cvt)
#define WAIT_STEADY  { if (PACKED) asm volatile("s_waitcnt vmcnt(6)" ::: "memory");  \
                       else        asm volatile("s_waitcnt vmcnt(10)" ::: "memory"); }
#define WAIT_TAIL    { if (PACKED) asm volatile("s_waitcnt vmcnt(4)" ::: "memory");  \
                       else        asm volatile("s_waitcnt vmcnt(8)" ::: "memory"); }
#define STEP(AFc, AFn, u)                                                 \
    {                                                                     \
        int rc1 = rc + 1; if (rc1 == 3) rc1 = 0;                          \
        int rc2 = rc1 + 1; if (rc2 == 3) rc2 = 0;                         \
        if ((u) + 2 < NT) STAGEB((u) + 2, rc2);                           \
        if ((u) + 1 < NT) LOADA(AFn, (u) + 1);                            \
        short8 bf_[4];                                                    \
        _Pragma("unroll")                                                 \
        for (int n = 0; n < 4; ++n)                                       \
            bf_[n] = *(const short8*)(&Bs[rc][(wn * 64 + n * 16 + r16) * 32 + gx]); \
        asm volatile("s_waitcnt lgkmcnt(0)" ::: "memory");                \
        __builtin_amdgcn_sched_barrier(0);                                \
        MFMA16(AFc, bf_);                                                 \
        if ((u) + 2 < NT)      { WAIT_STEADY; }                           \
        else if ((u) + 1 < NT) { WAIT_TAIL; }                             \
        else { asm volatile("s_waitcnt vmcnt(0)" ::: "memory"); }         \
        __builtin_amdgcn_s_barrier();                                     \
        rc = rc1;                                                         \
    }

    short8 afP[4], afQ[4];
    // ---- prologue: stage B(0), B(1); load A(0); wait B(0); barrier ----
    STAGEB(0, 0);
    STAGEB(1, 1);
    LOADA(afP, 0);
    WAIT_STEADY;
    __builtin_amdgcn_s_barrier();

    int rc = 0;
    for (int u = 0; u < NT; u += 2) {
        STEP(afP, afQ, u);
        STEP(afQ, afP, u + 1);
    }

#undef STAGEB
#undef LOADA
#undef MFMA16
#undef WAIT_STEADY
#undef WAIT_TAIL
#undef STEP

    // ---- epilogue: tanh, dot ww, 16-lane reduce, per-(x,wn) partial store ----
    float swv[4], wwv[4];
#pragma unroll
    for (int n = 0; n < 4; ++n) {
        const int w = w0 + wn * 64 + n * 16 + r16;
        float sv = 0.f;
#pragma unroll
        for (int q = 0; q < 4; ++q)
            sv += SWp[((size_t)q * B_DIM + b) * DIMW + w];
        swv[n] = sv;
        wwv[n] = ww[w];
    }
#pragma unroll
    for (int m = 0; m < 4; ++m) {
#pragma unroll
        for (int reg = 0; reg < 4; ++reg) {
            float s = 0.f;
#pragma unroll
            for (int n = 0; n < 4; ++n)
                s = fmaf(fast_tanh(acc[m][n][reg] + swv[n]), wwv[n], s);
            s += __shfl_xor(s, 1, 64);
            s += __shfl_xor(s, 2, 64);
            s += __shfl_xor(s, 4, 64);
            s += __shfl_xor(s, 8, 64);
            if (r16 == 0) {
                const int trow = t0 + wm * 64 + m * 16 + g * 4 + reg;
                ep[((size_t)(x * 2 + wn) * B_DIM + b) * T_DIM + trow] = s;
            }
        }
    }
}

// ---------------- softmax over t per batch (sums 8 e-partials) ----------------
__device__ __forceinline__ float decode_beta(const void* p) {
    const int iv = *(const int*)p;
    const float fv = __int_as_float(iv);
    const float afv = fabsf(fv);
    if (afv >= 1e-6f && afv <= 1e6f) return fv;
    return (float)iv;
}

__global__ void k_softmax(const float* __restrict__ ep, const void* __restrict__ beta_p,
                          float* __restrict__ out) {
    const int b = blockIdx.x;
    const float beta = decode_beta(beta_p);
    __shared__ float redm[4];
    __shared__ float reds[4];
    float v[4];
    float m = -INFINITY;
#pragma unroll
    for (int i = 0; i < 4; ++i) {
        const int t = threadIdx.x * 4 + i;
        float ev = 0.f;
#pragma unroll
        for (int xq = 0; xq < 8; ++xq)
            ev += ep[((size_t)xq * B_DIM + b) * T_DIM + t];
        v[i] = beta * ev;
        m = fmaxf(m, v[i]);
    }
    for (int off = 1; off < 64; off <<= 1) m = fmaxf(m, __shfl_xor(m, off, 64));
    const int wid = threadIdx.x >> 6, lane = threadIdx.x & 63;
    if (lane == 0) redm[wid] = m;
    __syncthreads();
    m = fmaxf(fmaxf(redm[0], redm[1]), fmaxf(redm[2], redm[3]));
    float s = 0.f;
    float ex[4];
#pragma unroll
    for (int i = 0; i < 4; ++i) { ex[i] = expf(v[i] - m); s += ex[i]; }
    for (int off = 1; off < 64; off <<= 1) s += __shfl_xor(s, off, 64);
    if (lane == 0) reds[wid] = s;
    __syncthreads();
    s = reds[0] + reds[1] + reds[2] + reds[3];
    const float inv = 1.f / s;
#pragma unroll
    for (int i = 0; i < 4; ++i)
        out[(size_t)b * T_DIM + threadIdx.x * 4 + i] = ex[i] * inv;
}

extern "C" void kernel_launch(void* const* d_in, const int* in_sizes, int n_in,
                              void* d_out, int out_size, void* d_ws, size_t ws_size,
                              hipStream_t stream) {
    const float* F      = (const float*)d_in[0];
    const float* a_prev = (const float*)d_in[1];
    const float* s_prev = (const float*)d_in[2];
    const float* h      = (const float*)d_in[3];
    const float* Ww     = (const float*)d_in[4];
    const float* Vw     = (const float*)d_in[5];
    const float* Vb     = (const float*)d_in[6];
    const float* Uw     = (const float*)d_in[7];
    const float* ww     = (const float*)d_in[8];
    const void*  beta_p = d_in[9];
    float* out = (float*)d_out;

    char* ws = (char*)d_ws;
    unsigned short* GT  = (unsigned short*)(ws);                        // 1 MB
    unsigned short* VwT = (unsigned short*)(ws + (1u << 20));           // 512 KB
    unsigned short* P   = (unsigned short*)(ws + (1u << 20) + (512u << 10));  // 1 MB
    float* SWp = (float*)(ws + (2u << 20) + (512u << 10));              // 256 KB
    float* ep  = (float*)(ws + (2u << 20) + (768u << 10));              // 1 MB (8 partials)
    unsigned short* hB = (unsigned short*)(ws + (4u << 20));            // 32 MB if available

    const bool big = ws_size >= (36ull << 20);

    k_G_gt    <<<dim3(64, 2),  256, 0, stream>>>(F, Uw, GT);
    k_pack_vwT<<<dim3(16, 16), 256, 0, stream>>>(Vw, VwT);
    k_pack_a  <<<dim3(256),    256, 0, stream>>>(a_prev, P);
    k_SW      <<<dim3(32, 4),  256, 0, stream>>>(s_prev, Ww, Vb, SWp);
    if (big) {
        k_pack_h<<<dim3(2048), 256, 0, stream>>>(h, hB);
        k_main<true><<<dim3(1024), 256, 0, stream>>>(h, hB, VwT, GT, P, SWp, ww, ep);
    } else {
        k_main<false><<<dim3(1024), 256, 0, stream>>>(h, hB, VwT, GT, P, SWp, ww, ep);
    }
    k_softmax <<<dim3(32),     256, 0, stream>>>(ep, beta_p, out);
}